// Round 1
// baseline (76.993 us; speedup 1.0000x reference)
//
#include <hip/hip_runtime.h>
#include <hip/hip_bf16.h>

// Problem dims (fixed by reference)
#define N_IN   1024     // K
#define N_P    1024     // N (= 32*32 lifted grid)
#define FILT   33
#define PAD    16

typedef __attribute__((ext_vector_type(8))) __bf16 bf16x8;
typedef __attribute__((ext_vector_type(4))) float  f32x4;

#define GLB(p) ((const __attribute__((address_space(1))) unsigned int*)(p))
#define LDSP(p) ((__attribute__((address_space(3))) unsigned int*)(p))

__device__ __forceinline__ unsigned short f2bf(float f) {
    union { __hip_bfloat16 h; unsigned short u; } cv;
    cv.h = __float2bfloat16(f);
    return cv.u;
}

// ---------------------------------------------------------------------------
// Kernel 1: per-row demean + std-normalize, fp32 -> bf16
// one wave per row, 4 waves per block
// ---------------------------------------------------------------------------
__global__ __launch_bounds__(256)
void normalize_kernel(const float* __restrict__ x, __hip_bfloat16* __restrict__ xn)
{
    const int lane = threadIdx.x & 63;
    const int row  = blockIdx.x * 4 + (threadIdx.x >> 6);

    const float4* xr = reinterpret_cast<const float4*>(x + (size_t)row * N_IN);
    float4 v[4];
    float s = 0.f, s2 = 0.f;
#pragma unroll
    for (int i = 0; i < 4; i++) {
        v[i] = xr[i * 64 + lane];
        s  += v[i].x + v[i].y + v[i].z + v[i].w;
        s2 += v[i].x * v[i].x + v[i].y * v[i].y + v[i].z * v[i].z + v[i].w * v[i].w;
    }
#pragma unroll
    for (int off = 32; off > 0; off >>= 1) {
        s  += __shfl_xor(s,  off, 64);
        s2 += __shfl_xor(s2, off, 64);
    }
    const float mu  = s * (1.0f / N_IN);
    const float var = fmaxf(s2 * (1.0f / N_IN) - mu * mu, 0.0f);
    const float inv = 1.0f / (sqrtf(var) + 1e-7f);

    ushort4* outv = reinterpret_cast<ushort4*>(xn + (size_t)row * N_IN);
#pragma unroll
    for (int i = 0; i < 4; i++) {
        ushort4 o;
        o.x = f2bf((v[i].x - mu) * inv);
        o.y = f2bf((v[i].y - mu) * inv);
        o.z = f2bf((v[i].z - mu) * inv);
        o.w = f2bf((v[i].w - mu) * inv);
        outv[i * 64 + lane] = o;
    }
}

// ---------------------------------------------------------------------------
// Kernel 2: Gaussian resolution filter + circular conv along n, fp32 -> bf16
// one block (256 threads) per p-row; row staged in LDS
// ---------------------------------------------------------------------------
__global__ __launch_bounds__(256)
void conv_kernel(const float* __restrict__ lm_raw, __hip_bfloat16* __restrict__ lm)
{
    __shared__ float row[N_IN];
    __shared__ float fw[FILT];
    const int tid = threadIdx.x;
    const int p   = blockIdx.x;

    if (tid < FILT) {
        float t = (tid - PAD) * (2.0f / FILT);
        float u = t * 10.0f;            // t / sigma0 (sigma0 = 0.1)
        fw[tid] = expf(-0.5f * u * u);
    }
    reinterpret_cast<float4*>(row)[tid] =
        reinterpret_cast<const float4*>(lm_raw + (size_t)p * N_IN)[tid];
    __syncthreads();

    float fsum = 0.f;
#pragma unroll
    for (int f = 0; f < FILT; f++) fsum += fw[f];
    const float inv = 1.0f / fsum;

    const int n0 = tid * 4;
    float o[4] = {0.f, 0.f, 0.f, 0.f};
#pragma unroll
    for (int f = 0; f < FILT; f++) {
        const float w = fw[f];
#pragma unroll
        for (int j = 0; j < 4; j++)
            o[j] += w * row[(n0 + j + f - PAD) & (N_IN - 1)];
    }
    ushort4 ov;
    ov.x = f2bf(o[0] * inv);
    ov.y = f2bf(o[1] * inv);
    ov.z = f2bf(o[2] * inv);
    ov.w = f2bf(o[3] * inv);
    reinterpret_cast<ushort4*>(lm + (size_t)p * N_IN)[tid] = ov;
}

// ---------------------------------------------------------------------------
// Kernel 3: GEMM  C[M,N] = A[M,K] * B[N,K]^T   (both operands K-contiguous)
// m97 structure: 128x128 tile, BK=32, 4 waves (2x2), each wave 64x64 output,
// global_load_lds width=16 staging, 16x16x32 bf16 MFMA, 4x4 frags/wave.
// ---------------------------------------------------------------------------
__global__ __launch_bounds__(256, 2)
void gemm_bt(const __hip_bfloat16* __restrict__ A,
             const __hip_bfloat16* __restrict__ B,
             float* __restrict__ C,
             int M, int N, int K)
{
    constexpr int BM = 128, BN = 128, BK = 32;
    __shared__ __hip_bfloat16 As[BM * BK];   // 8 KiB, linear row-major [128][32]
    __shared__ __hip_bfloat16 Bs[BN * BK];   // 8 KiB

    const int tid  = threadIdx.x;
    const int lane = tid & 63;
    const int wid  = tid >> 6;   // 0..3
    const int wr   = wid >> 1;   // wave row 0..1
    const int wc   = wid & 1;    // wave col 0..1

    const int bm = blockIdx.y * BM;
    const int bn = blockIdx.x * BN;

    // staging: wave `wid` stages rows [wid*32, wid*32+32) of each tile,
    // two global_load_lds calls of 16 rows each (64 lanes x 16B = 16 rows x 64B)
    const int srow = lane >> 2;          // 0..15
    const int scol = (lane & 3) * 8;     // bf16 elems within the 32-elem row
    const __hip_bfloat16* gA0 = A + (size_t)(bm + wid * 32 + srow) * K + scol;
    const __hip_bfloat16* gA1 = gA0 + (size_t)16 * K;
    const __hip_bfloat16* gB0 = B + (size_t)(bn + wid * 32 + srow) * K + scol;
    const __hip_bfloat16* gB1 = gB0 + (size_t)16 * K;
    __hip_bfloat16* lA0 = As + (wid * 32) * BK;
    __hip_bfloat16* lA1 = As + (wid * 32 + 16) * BK;
    __hip_bfloat16* lB0 = Bs + (wid * 32) * BK;
    __hip_bfloat16* lB1 = Bs + (wid * 32 + 16) * BK;

    f32x4 acc[4][4] = {};

    const bf16x8* Asv = reinterpret_cast<const bf16x8*>(As);
    const bf16x8* Bsv = reinterpret_cast<const bf16x8*>(Bs);
    const int lr = lane & 15;
    const int kb = lane >> 4;    // 0..3 (k-block of 8)

    for (int k0 = 0; k0 < K; k0 += BK) {
        __builtin_amdgcn_global_load_lds(GLB(gA0 + k0), LDSP(lA0), 16, 0, 0);
        __builtin_amdgcn_global_load_lds(GLB(gA1 + k0), LDSP(lA1), 16, 0, 0);
        __builtin_amdgcn_global_load_lds(GLB(gB0 + k0), LDSP(lB0), 16, 0, 0);
        __builtin_amdgcn_global_load_lds(GLB(gB1 + k0), LDSP(lB1), 16, 0, 0);
        __syncthreads();

        bf16x8 a[4], b[4];
#pragma unroll
        for (int m = 0; m < 4; m++) a[m] = Asv[(wr * 64 + m * 16 + lr) * 4 + kb];
#pragma unroll
        for (int n = 0; n < 4; n++) b[n] = Bsv[(wc * 64 + n * 16 + lr) * 4 + kb];
#pragma unroll
        for (int m = 0; m < 4; m++)
#pragma unroll
            for (int n = 0; n < 4; n++)
                acc[m][n] = __builtin_amdgcn_mfma_f32_16x16x32_bf16(a[m], b[n], acc[m][n], 0, 0, 0);
        __syncthreads();
    }

    // epilogue: C/D layout col = lane&15, row = (lane>>4)*4 + reg  [m89/m91]
    const int crow0 = (lane >> 4) * 4;
    const int ccol  = lane & 15;
#pragma unroll
    for (int m = 0; m < 4; m++)
#pragma unroll
        for (int n = 0; n < 4; n++) {
#pragma unroll
            for (int r = 0; r < 4; r++) {
                const int row = bm + wr * 64 + m * 16 + crow0 + r;
                const int col = bn + wc * 64 + n * 16 + ccol;
                C[(size_t)row * N + col] = acc[m][n][r];
            }
        }
}

// ---------------------------------------------------------------------------
extern "C" void kernel_launch(void* const* d_in, const int* in_sizes, int n_in,
                              void* d_out, int out_size, void* d_ws, size_t ws_size,
                              hipStream_t stream) {
    const float* x      = (const float*)d_in[0];   // [M, 1024] fp32
    const float* lm_raw = (const float*)d_in[1];   // [32, 32, 1024] fp32
    float* out = (float*)d_out;                    // [M, 32, 32] fp32

    const int M = in_sizes[0] / N_IN;              // 16384

    // workspace layout: xn bf16 [M,1024] (32 MiB) | lm bf16 [1024,1024] (2 MiB)
    __hip_bfloat16* xn = (__hip_bfloat16*)d_ws;
    __hip_bfloat16* lm = (__hip_bfloat16*)((char*)d_ws + (size_t)M * N_IN * 2);

    normalize_kernel<<<M / 4, 256, 0, stream>>>(x, xn);
    conv_kernel<<<N_P, 256, 0, stream>>>(lm_raw, lm);

    dim3 grid(N_P / 128, M / 128);   // (8, 128)
    gemm_bt<<<grid, dim3(256), 0, stream>>>(xn, lm, out, M, N_P, N_IN);
}

// Round 4
// 65.581 us; speedup vs baseline: 1.1740x; 1.1740x over previous
//
#include <hip/hip_runtime.h>
#include <hip/hip_bf16.h>

// Problem dims (fixed by reference)
#define N_IN   1024     // K
#define N_P    1024     // N (= 32*32 lifted grid)
#define FILT   33
#define PAD    16

typedef __attribute__((ext_vector_type(8))) __bf16 bf16x8;
typedef __attribute__((ext_vector_type(4))) float  f32x4;

#define GLB(p) ((const __attribute__((address_space(1))) unsigned int*)(p))
#define LDSP(p) ((__attribute__((address_space(3))) unsigned int*)(p))

__device__ __forceinline__ unsigned short f2bf(float f) {
    union { __hip_bfloat16 h; unsigned short u; } cv;
    cv.h = __float2bfloat16(f);
    return cv.u;
}

// ---------------------------------------------------------------------------
// Kernel 1: per-row demean + std-normalize, fp32 -> bf16
// ---------------------------------------------------------------------------
__global__ __launch_bounds__(256)
void normalize_kernel(const float* __restrict__ x, __hip_bfloat16* __restrict__ xn)
{
    const int lane = threadIdx.x & 63;
    const int row  = blockIdx.x * 4 + (threadIdx.x >> 6);

    const float4* xr = reinterpret_cast<const float4*>(x + (size_t)row * N_IN);
    float4 v[4];
    float s = 0.f, s2 = 0.f;
#pragma unroll
    for (int i = 0; i < 4; i++) {
        v[i] = xr[i * 64 + lane];
        s  += v[i].x + v[i].y + v[i].z + v[i].w;
        s2 += v[i].x * v[i].x + v[i].y * v[i].y + v[i].z * v[i].z + v[i].w * v[i].w;
    }
#pragma unroll
    for (int off = 32; off > 0; off >>= 1) {
        s  += __shfl_xor(s,  off, 64);
        s2 += __shfl_xor(s2, off, 64);
    }
    const float mu  = s * (1.0f / N_IN);
    const float var = fmaxf(s2 * (1.0f / N_IN) - mu * mu, 0.0f);
    const float inv = 1.0f / (sqrtf(var) + 1e-7f);

    ushort4* outv = reinterpret_cast<ushort4*>(xn + (size_t)row * N_IN);
#pragma unroll
    for (int i = 0; i < 4; i++) {
        ushort4 o;
        o.x = f2bf((v[i].x - mu) * inv);
        o.y = f2bf((v[i].y - mu) * inv);
        o.z = f2bf((v[i].z - mu) * inv);
        o.w = f2bf((v[i].w - mu) * inv);
        outv[i * 64 + lane] = o;
    }
}

// ---------------------------------------------------------------------------
// Kernel 2: Gaussian resolution filter + circular conv along n, fp32 -> bf16
// ---------------------------------------------------------------------------
__global__ __launch_bounds__(256)
void conv_kernel(const float* __restrict__ lm_raw, __hip_bfloat16* __restrict__ lm)
{
    __shared__ float row[N_IN];
    __shared__ float fw[FILT];
    const int tid = threadIdx.x;
    const int p   = blockIdx.x;

    if (tid < FILT) {
        float t = (tid - PAD) * (2.0f / FILT);
        float u = t * 10.0f;            // t / sigma0 (sigma0 = 0.1)
        fw[tid] = expf(-0.5f * u * u);
    }
    reinterpret_cast<float4*>(row)[tid] =
        reinterpret_cast<const float4*>(lm_raw + (size_t)p * N_IN)[tid];
    __syncthreads();

    float fsum = 0.f;
#pragma unroll
    for (int f = 0; f < FILT; f++) fsum += fw[f];
    const float inv = 1.0f / fsum;

    const int n0 = tid * 4;
    float o[4] = {0.f, 0.f, 0.f, 0.f};
#pragma unroll
    for (int f = 0; f < FILT; f++) {
        const float w = fw[f];
#pragma unroll
        for (int j = 0; j < 4; j++)
            o[j] += w * row[(n0 + j + f - PAD) & (N_IN - 1)];
    }
    ushort4 ov;
    ov.x = f2bf(o[0] * inv);
    ov.y = f2bf(o[1] * inv);
    ov.z = f2bf(o[2] * inv);
    ov.w = f2bf(o[3] * inv);
    reinterpret_cast<ushort4*>(lm + (size_t)p * N_IN)[tid] = ov;
}

// ---------------------------------------------------------------------------
// Kernel 3: GEMM  C[M,N] = A[M,K] * B[N,K]^T, deep-pipelined.
// 256x256 tile, BK=32, 512 thr (8 waves 2x4), per-wave 128x64 out.
// 4-deep LDS ring (4 x 32KB), prefetch distance 3 K-tiles,
// counted s_waitcnt vmcnt(8) + raw s_barrier (loads in flight across barrier).
// LDS XOR swizzle (slot ^= (row>>1)&3): linear gload_lds dest +
// pre-swizzled global source + swizzled ds_read (rule 21). 2-way = free.
// ---------------------------------------------------------------------------
__global__ __launch_bounds__(512, 2)
void gemm_bt2(const __hip_bfloat16* __restrict__ A,
              const __hip_bfloat16* __restrict__ B,
              float* __restrict__ C,
              int M, int N, int K)
{
    constexpr int BK = 32;                 // K-tile; rows are 64B (4 x 16B slots)
    __shared__ char smem[4][32768];        // ring: per buf = A[256][32] | B[256][32]

    const int tid = threadIdx.x;
    const int l   = tid & 63;
    const int w   = tid >> 6;    // 0..7
    const int wr  = w >> 2;      // 0..1
    const int wc  = w & 3;       // 0..3

    // T1: bijective XCD swizzle (nwg=256 divisible by 8)
    const int o    = blockIdx.x;
    const int lin  = (o & 7) * (gridDim.x >> 3) + (o >> 3);
    const int tn   = lin & 3;          // N/256 = 4
    const int tm   = lin >> 2;
    const size_t bm = (size_t)tm * 256;
    const size_t bn = (size_t)tn * 256;

    // ---- staging geometry (per-lane global source, pre-swizzled) ----
    // LDS linear pos L = c*8192 + w*1024 + 16*l  (within 16KB half-region)
    // row = L>>6 = c*128 + w*16 + (l>>2); swizzle key = (row>>1)&3 = (l>>3)&3
    const int srow = w * 16 + (l >> 2);                 // + c*128
    const int scol = 16 * ((l & 3) ^ ((l >> 3) & 3));   // swizzled 16B slot
    const char* gA = (const char*)(A + (bm + srow) * (size_t)K) + scol;
    const char* gB = (const char*)(B + (bn + srow) * (size_t)K) + scol;
    const size_t rowstep = (size_t)128 * K * 2;         // c=1 offset (bytes)

#define STAGE(t, b) do {                                                        \
    const char* a0_ = gA + (size_t)(t) * (BK * 2);                              \
    const char* b0_ = gB + (size_t)(t) * (BK * 2);                              \
    char* La_ = &smem[(b)][0]     + w * 1024;                                   \
    char* Lb_ = &smem[(b)][16384] + w * 1024;                                   \
    __builtin_amdgcn_global_load_lds(GLB(a0_),           LDSP(La_),        16, 0, 0); \
    __builtin_amdgcn_global_load_lds(GLB(a0_ + rowstep), LDSP(La_ + 8192), 16, 0, 0); \
    __builtin_amdgcn_global_load_lds(GLB(b0_),           LDSP(Lb_),        16, 0, 0); \
    __builtin_amdgcn_global_load_lds(GLB(b0_ + rowstep), LDSP(Lb_ + 8192), 16, 0, 0); \
} while (0)

    // ---- fragment-read geometry (swizzled ds_read, same involution) ----
    const int lr = l & 15;
    const int kb = l >> 4;                               // k-block of 8 elems
    const int rslot = 16 * (kb ^ ((lr >> 1) & 3));       // swizzled slot byte

    f32x4 acc[8][4] = {};

    const int NT = K / BK;                               // 32

    STAGE(0, 0);
    STAGE(1, 1);
    STAGE(2, 2);

    for (int t = 0; t < NT; ++t) {
        // my previous-tile ds_reads must be complete before I pass the barrier
        asm volatile("s_waitcnt lgkmcnt(0)" ::: "memory");
        // tile t's 4 gloads are the oldest outstanding; t+1,t+2 stay in flight
        if (t < NT - 2)       asm volatile("s_waitcnt vmcnt(8)" ::: "memory");
        else if (t == NT - 2) asm volatile("s_waitcnt vmcnt(4)" ::: "memory");
        else                  asm volatile("s_waitcnt vmcnt(0)" ::: "memory");
        __builtin_amdgcn_s_barrier();
        asm volatile("" ::: "memory");   // nothing (incl. LDS reads) crosses the barrier

        if (t + 3 < NT) STAGE(t + 3, (t + 3) & 3);

        const char* Ab = &smem[t & 3][0];
        const char* Bb = &smem[t & 3][16384];

        bf16x8 bfr[4], afr[8];
#pragma unroll
        for (int n = 0; n < 4; n++)
            bfr[n] = *(const bf16x8*)(Bb + (wc * 64 + n * 16 + lr) * 64 + rslot);
#pragma unroll
        for (int m = 0; m < 8; m++)
            afr[m] = *(const bf16x8*)(Ab + (wr * 128 + m * 16 + lr) * 64 + rslot);

#pragma unroll
        for (int m = 0; m < 8; m++)
#pragma unroll
            for (int n = 0; n < 4; n++)
                acc[m][n] = __builtin_amdgcn_mfma_f32_16x16x32_bf16(afr[m], bfr[n], acc[m][n], 0, 0, 0);
    }
#undef STAGE

    // epilogue: C/D layout col = lane&15, row = (lane>>4)*4 + reg  [m89/m91]
    const int crow = (l >> 4) * 4;
    const int ccol = l & 15;
#pragma unroll
    for (int m = 0; m < 8; m++)
#pragma unroll
        for (int n = 0; n < 4; n++) {
#pragma unroll
            for (int r = 0; r < 4; r++) {
                const size_t row = bm + wr * 128 + m * 16 + crow + r;
                const size_t col = bn + wc * 64 + n * 16 + ccol;
                C[row * N + col] = acc[m][n][r];
            }
        }
}

// ---------------------------------------------------------------------------
extern "C" void kernel_launch(void* const* d_in, const int* in_sizes, int n_in,
                              void* d_out, int out_size, void* d_ws, size_t ws_size,
                              hipStream_t stream) {
    const float* x      = (const float*)d_in[0];   // [M, 1024] fp32
    const float* lm_raw = (const float*)d_in[1];   // [32, 32, 1024] fp32
    float* out = (float*)d_out;                    // [M, 32, 32] fp32

    const int M = in_sizes[0] / N_IN;              // 16384

    // workspace layout: xn bf16 [M,1024] (32 MiB) | lm bf16 [1024,1024] (2 MiB)
    __hip_bfloat16* xn = (__hip_bfloat16*)d_ws;
    __hip_bfloat16* lm = (__hip_bfloat16*)((char*)d_ws + (size_t)M * N_IN * 2);

    normalize_kernel<<<M / 4, 256, 0, stream>>>(x, xn);
    conv_kernel<<<N_P, 256, 0, stream>>>(lm_raw, lm);

    const int nblk = (M / 256) * (N_P / 256);      // 64 * 4 = 256
    gemm_bt2<<<nblk, dim3(512), 0, stream>>>(xn, lm, out, M, N_P, N_IN);
}